// Round 3
// baseline (957.432 us; speedup 1.0000x reference)
//
#include <hip/hip_runtime.h>
#include <hip/hip_bf16.h>
#include <math.h>

// Problem constants (from reference file)
#define BB 16
#define LL 3136
#define CC 96
#define HH 56
#define WW 56
#define RR 3
#define RTOT 5
#define EE 131072
#define NR (BB*LL)            // 50176 rows
#define NSEG (LL*RR)          // 9408 segments
#define FFN 384

// ---------------- LayerNorm: one wave per row (96 elems) ----------------
__global__ __launch_bounds__(256) void ln_kernel(const float* __restrict__ x,
                                                 const float* __restrict__ g,
                                                 const float* __restrict__ bta,
                                                 float* __restrict__ out, int nrows)
{
    int wave = threadIdx.x >> 6;
    int lane = threadIdx.x & 63;
    int row  = blockIdx.x * 4 + wave;
    if (row >= nrows) return;
    const float* xr = x + (size_t)row * CC;
    float v0 = xr[lane];
    float v1 = (lane < 32) ? xr[64 + lane] : 0.f;
    float s = v0 + v1;
    #pragma unroll
    for (int off = 32; off; off >>= 1) s += __shfl_xor(s, off);
    float mean = s * (1.f / 96.f);
    float d0 = v0 - mean;
    float d1 = (lane < 32) ? (v1 - mean) : 0.f;
    float q = d0 * d0 + d1 * d1;
    #pragma unroll
    for (int off = 32; off; off >>= 1) q += __shfl_xor(q, off);
    float rstd = rsqrtf(q * (1.f / 96.f) + 1e-5f);
    out[(size_t)row * CC + lane] = d0 * rstd * g[lane] + bta[lane];
    if (lane < 32)
        out[(size_t)row * CC + 64 + lane] = d1 * rstd * g[64 + lane] + bta[64 + lane];
}

// ---------------- GEMM: out = act(A@B + bias) (+res), fp32 ----------------
// BM=128, BN=96, BK=16, 128 threads, 8x12 microtile, all-b128 LDS reads.
// PERM=true writes output row (b*LL+l) to location (l*BB+b) -> [L,B,C] layout.
__device__ __forceinline__ float gelu_exact(float v) {
    return 0.5f * v * (1.0f + erff(v * 0.70710678118654752440f));
}

template<int ACT, bool RES, bool PERM>
__global__ __launch_bounds__(128, 3) void gemm_kernel(const float* __restrict__ A,
                                                      const float* __restrict__ Bm,
                                                      const float* __restrict__ bias,
                                                      const float* __restrict__ res,
                                                      float* __restrict__ out,
                                                      int M, int N, int K)
{
    const int BM = 128, BN = 96, BK = 16, TM = 8, TN = 12;
    __shared__ float As[BK][BM];   // transposed A tile, 8 KB
    __shared__ float Bs[BK][BN];   // 6 KB
    int bm = blockIdx.x * BM;
    int bn = blockIdx.y * BN;
    int tid = threadIdx.x;         // 0..127
    int tx = tid & 7;              // 8 lanes in N; col base = tx*12 (48B aligned)
    int ty = tid >> 3;             // 16 in M; row base = ty*8 (32B aligned)
    float acc[TM][TN];
    #pragma unroll
    for (int i = 0; i < TM; i++)
        #pragma unroll
        for (int j = 0; j < TN; j++) acc[i][j] = 0.f;

    for (int k0 = 0; k0 < K; k0 += BK) {
        // A tile: each thread loads one full row chunk of 16 floats (4x float4)
        {
            const float* ap = A + (size_t)(bm + tid) * K + k0;
            float4 q0 = *(const float4*)(ap + 0);
            float4 q1 = *(const float4*)(ap + 4);
            float4 q2 = *(const float4*)(ap + 8);
            float4 q3 = *(const float4*)(ap + 12);
            As[ 0][tid] = q0.x; As[ 1][tid] = q0.y; As[ 2][tid] = q0.z; As[ 3][tid] = q0.w;
            As[ 4][tid] = q1.x; As[ 5][tid] = q1.y; As[ 6][tid] = q1.z; As[ 7][tid] = q1.w;
            As[ 8][tid] = q2.x; As[ 9][tid] = q2.y; As[10][tid] = q2.z; As[11][tid] = q2.w;
            As[12][tid] = q3.x; As[13][tid] = q3.y; As[14][tid] = q3.z; As[15][tid] = q3.w;
        }
        // B tile: 16x96 = 384 float4s, 3 per thread
        #pragma unroll
        for (int e = tid; e < BK * BN / 4; e += 128) {
            int rr = e / 24, c4 = e - rr * 24;
            *(float4*)&Bs[rr][c4 * 4] = *(const float4*)&Bm[(size_t)(k0 + rr) * N + bn + c4 * 4];
        }
        __syncthreads();
        #pragma unroll
        for (int kk = 0; kk < BK; ++kk) {
            float a[TM], b[TN];
            *(float4*)&a[0] = *(const float4*)&As[kk][ty * 8 + 0];
            *(float4*)&a[4] = *(const float4*)&As[kk][ty * 8 + 4];
            *(float4*)&b[0] = *(const float4*)&Bs[kk][tx * 12 + 0];
            *(float4*)&b[4] = *(const float4*)&Bs[kk][tx * 12 + 4];
            *(float4*)&b[8] = *(const float4*)&Bs[kk][tx * 12 + 8];
            #pragma unroll
            for (int i = 0; i < TM; i++)
                #pragma unroll
                for (int j = 0; j < TN; j++)
                    acc[i][j] += a[i] * b[j];
        }
        __syncthreads();
    }

    int cbase = bn + tx * 12;
    float bv[TN];
    #pragma unroll
    for (int j = 0; j < TN; j++) bv[j] = bias[cbase + j];
    #pragma unroll
    for (int i = 0; i < TM; i++) {
        int row = bm + ty * 8 + i;
        size_t orow;
        if (PERM) {
            int b = row / LL;
            int l = row - b * LL;
            orow = (size_t)l * BB + b;
        } else {
            orow = (size_t)row;
        }
        float v[TN];
        #pragma unroll
        for (int j = 0; j < TN; j++) {
            float val = acc[i][j] + bv[j];
            if (ACT == 1) val = gelu_exact(val);
            v[j] = val;
        }
        if (RES) {
            float4 r0 = *(const float4*)&res[(size_t)row * N + cbase + 0];
            float4 r1 = *(const float4*)&res[(size_t)row * N + cbase + 4];
            float4 r2 = *(const float4*)&res[(size_t)row * N + cbase + 8];
            v[0] += r0.x; v[1] += r0.y; v[2]  += r0.z; v[3]  += r0.w;
            v[4] += r1.x; v[5] += r1.y; v[6]  += r1.z; v[7]  += r1.w;
            v[8] += r2.x; v[9] += r2.y; v[10] += r2.z; v[11] += r2.w;
        }
        float* op = out + orow * N + cbase;
        *(float4*)(op + 0) = *(float4*)&v[0];
        *(float4*)(op + 4) = *(float4*)&v[4];
        *(float4*)(op + 8) = *(float4*)&v[8];
    }
}

// ---------------- Gate: wave per row, 5 shuffle-reduced dots ----------------
__global__ __launch_bounds__(256) void gate_kernel(const float* __restrict__ h,
                                                   const float* __restrict__ gw,
                                                   const float* __restrict__ gb,
                                                   float* __restrict__ gate)
{
    int wave = threadIdx.x >> 6;
    int lane = threadIdx.x & 63;
    int row  = blockIdx.x * 4 + wave;
    if (row >= NR) return;
    const float* hr = h + (size_t)row * CC;
    float v0 = hr[lane];
    float v1 = (lane < 32) ? hr[64 + lane] : 0.f;
    #pragma unroll
    for (int r = 0; r < RTOT; r++) {
        float s = v0 * gw[lane * RTOT + r];
        if (lane < 32) s += v1 * gw[(64 + lane) * RTOT + r];
        #pragma unroll
        for (int off = 32; off; off >>= 1) s += __shfl_xor(s, off);
        if (lane == r) gate[(size_t)row * RTOT + r] = 1.f / (1.f + expf(-(s + gb[r])));
    }
}

// ---------------- CSR build ----------------
__global__ void hist_kernel(const int* __restrict__ ei, const int* __restrict__ et,
                            int* __restrict__ cnt)
{
    int e = blockIdx.x * 256 + threadIdx.x;
    if (e >= EE) return;
    int dst = ei[EE + e];
    int r   = et[e];
    atomicAdd(&cnt[dst * RR + r], 1);
}

// 1024-thread hierarchical block scan: 10 iterations over NSEG=9408
__global__ __launch_bounds__(1024) void scan_kernel(const int* __restrict__ cnt,
                                                    int* __restrict__ colptr,
                                                    float* __restrict__ invcnt)
{
    __shared__ int wsum[16];
    int tid = threadIdx.x, wid = tid >> 6, lane = tid & 63;
    int carry = 0;
    for (int base = 0; base < NSEG; base += 1024) {
        int idx = base + tid;
        int v = (idx < NSEG) ? cnt[idx] : 0;
        if (idx < NSEG) invcnt[idx] = 1.f / (float)max(v, 1);
        int sc = v;
        #pragma unroll
        for (int off = 1; off < 64; off <<= 1) {
            int o = __shfl_up(sc, off);
            if (lane >= off) sc += o;
        }
        if (lane == 63) wsum[wid] = sc;
        __syncthreads();
        if (wid == 0) {
            int w = (lane < 16) ? wsum[lane] : 0;
            #pragma unroll
            for (int off = 1; off < 16; off <<= 1) {
                int o = __shfl_up(w, off);
                if (lane >= off) w += o;
            }
            if (lane < 16) wsum[lane] = w;
        }
        __syncthreads();
        int woff = (wid > 0) ? wsum[wid - 1] : 0;
        if (idx < NSEG) colptr[idx] = carry + woff + sc - v;   // exclusive
        carry += wsum[15];
        __syncthreads();
    }
    if (tid == 0) colptr[NSEG] = carry;
}

__global__ void scatter_kernel(const int* __restrict__ ei, const int* __restrict__ et,
                               const int* __restrict__ colptr, int* __restrict__ fill,
                               int* __restrict__ esorted)
{
    int e = blockIdx.x * 256 + threadIdx.x;
    if (e >= EE) return;
    int src = ei[e];
    int dst = ei[EE + e];
    int seg = dst * RR + et[e];
    int pos = colptr[seg] + atomicAdd(&fill[seg], 1);
    esorted[pos] = src;
}

// ---------------- Aggregation + depthwise convs + gating → updg [B,L,480] ----------------
// v is in [L,B,C] layout (vperm). One block per l, 96 threads (channel),
// each thread keeps all 16 batch accumulators in registers.
__global__ __launch_bounds__(96) void aggconv_kernel(const float* __restrict__ vp,
                               const float* __restrict__ gate,
                               const int* __restrict__ colptr, const int* __restrict__ esorted,
                               const float* __restrict__ invcnt,
                               const float* __restrict__ k3, const float* __restrict__ b3,
                               const float* __restrict__ k5, const float* __restrict__ b5,
                               float* __restrict__ updg)
{
    int l = blockIdx.x;
    int c = threadIdx.x;     // channel 0..95
    __shared__ float gs[BB][RTOT];
    if (c < BB * RTOT) {
        int b = c / RTOT, r = c - b * RTOT;
        gs[b][r] = gate[((size_t)b * LL + l) * RTOT + r];
    }
    __syncthreads();

    // graph relations: mean-aggregate with batch-register blocking
    #pragma unroll
    for (int r = 0; r < RR; r++) {
        int s0 = colptr[l * RR + r], s1 = colptr[l * RR + r + 1];
        float acc[BB];
        #pragma unroll
        for (int b = 0; b < BB; b++) acc[b] = 0.f;
        int src = (s0 < s1) ? esorted[s0] : 0;
        for (int e = s0; e < s1; e++) {
            int nsrc = (e + 1 < s1) ? esorted[e + 1] : 0;
            const float* p = vp + (size_t)src * (BB * CC) + c;
            #pragma unroll
            for (int b = 0; b < BB; b++) acc[b] += p[b * CC];
            src = nsrc;
        }
        float inv = invcnt[l * RR + r];
        #pragma unroll
        for (int b = 0; b < BB; b++)
            updg[((size_t)b * LL + l) * (RTOT * CC) + r * CC + c] = acc[b] * inv * gs[b][r];
    }

    // context: 5x5 depthwise with fused 3x3 (3x3 taps are a subset)
    int h0 = l / WW, w0 = l - (l / WW) * WW;
    float a3[BB], a5[BB];
    float bb3 = b3[c], bb5 = b5[c];
    #pragma unroll
    for (int b = 0; b < BB; b++) { a3[b] = bb3; a5[b] = bb5; }
    #pragma unroll
    for (int kh = -2; kh <= 2; kh++) {
        int hh = h0 + kh; if (hh < 0 || hh >= HH) continue;
        #pragma unroll
        for (int kw = -2; kw <= 2; kw++) {
            int ww = w0 + kw; if (ww < 0 || ww >= WW) continue;
            float w5 = k5[c * 25 + (kh + 2) * 5 + (kw + 2)];
            bool in3 = (kh >= -1 && kh <= 1 && kw >= -1 && kw <= 1);
            float w3 = in3 ? k3[c * 9 + (kh + 1) * 3 + (kw + 1)] : 0.f;
            const float* p = vp + (size_t)(hh * WW + ww) * (BB * CC) + c;
            #pragma unroll
            for (int b = 0; b < BB; b++) {
                float t = p[b * CC];
                a5[b] += t * w5;
                a3[b] += t * w3;
            }
        }
    }
    #pragma unroll
    for (int b = 0; b < BB; b++) {
        size_t ob = ((size_t)b * LL + l) * (RTOT * CC);
        updg[ob + 3 * CC + c] = a3[b] * gs[b][3];
        updg[ob + 4 * CC + c] = a5[b] * gs[b][4];
    }
}

// ---------------- launch ----------------
extern "C" void kernel_launch(void* const* d_in, const int* in_sizes, int n_in,
                              void* d_out, int out_size, void* d_ws, size_t ws_size,
                              hipStream_t stream)
{
    const float* x       = (const float*)d_in[0];
    const int*   ei      = (const int*)d_in[1];
    const int*   et      = (const int*)d_in[2];
    // d_in[3], d_in[4] = H, W (hardcoded 56)
    const float* n1g     = (const float*)d_in[5];
    const float* n1b     = (const float*)d_in[6];
    const float* value_w = (const float*)d_in[7];
    const float* value_b = (const float*)d_in[8];
    const float* gate_w  = (const float*)d_in[9];
    const float* gate_b  = (const float*)d_in[10];
    const float* k3      = (const float*)d_in[11];
    const float* b3      = (const float*)d_in[12];
    const float* k5      = (const float*)d_in[13];
    const float* b5      = (const float*)d_in[14];
    const float* rel_w   = (const float*)d_in[15];
    const float* rel_b   = (const float*)d_in[16];
    const float* proj_w  = (const float*)d_in[17];
    const float* proj_b  = (const float*)d_in[18];
    const float* n2g     = (const float*)d_in[19];
    const float* n2b     = (const float*)d_in[20];
    const float* fc1_w   = (const float*)d_in[21];
    const float* fc1_b   = (const float*)d_in[22];
    const float* fc2_w   = (const float*)d_in[23];
    const float* fc2_b   = (const float*)d_in[24];
    float* out = (float*)d_out;

    // workspace layout (floats)
    float* w = (float*)d_ws;
    const size_t SZ_ROW = (size_t)NR * CC;            // 4,816,896
    float* hbuf   = w;                                 // h, later g1, later h2
    float* vbuf   = hbuf + SZ_ROW;                     // vperm [L,B,C], later x1 [B,L,C]
    float* gateb  = vbuf + SZ_ROW;                     // [NR,5]
    float* updg   = gateb + (size_t)NR * RTOT;         // [NR,480], later ffn hidden [NR,384]
    int*   ibase  = (int*)(updg + (size_t)NR * RTOT * CC);
    int*   cnt     = ibase;                            // [NSEG]
    int*   colptr  = cnt + NSEG;                       // [NSEG+1]
    int*   fill    = colptr + NSEG + 1;                // [NSEG]
    int*   esorted = fill + NSEG;                      // [E]
    float* invcnt  = (float*)(esorted + EE);           // [NSEG]

    // zero the counters
    hipMemsetAsync(cnt, 0, NSEG * sizeof(int), stream);
    hipMemsetAsync(fill, 0, NSEG * sizeof(int), stream);

    // 1. LN1
    ln_kernel<<<(NR + 3) / 4, 256, 0, stream>>>(x, n1g, n1b, hbuf, NR);
    // 2. vperm[l,b,:] = (h @ value_w + value_b)[b*LL+l]  (PERM write)
    gemm_kernel<0, false, true><<<dim3(NR / 128, 1), 128, 0, stream>>>(hbuf, value_w, value_b, nullptr, vbuf, NR, CC, CC);
    // 3. gates
    gate_kernel<<<(NR + 3) / 4, 256, 0, stream>>>(hbuf, gate_w, gate_b, gateb);
    // 4. CSR build
    hist_kernel<<<EE / 256, 256, 0, stream>>>(ei, et, cnt);
    scan_kernel<<<1, 1024, 0, stream>>>(cnt, colptr, invcnt);
    scatter_kernel<<<EE / 256, 256, 0, stream>>>(ei, et, colptr, fill, esorted);
    // 5. aggregation + convs + gating (batch-register blocked)
    aggconv_kernel<<<dim3(LL), 96, 0, stream>>>(vbuf, gateb, colptr, esorted, invcnt,
                                                k3, b3, k5, b5, updg);
    // 6. g1 = gelu(updg @ rel_w + rel_b)  (into hbuf)
    gemm_kernel<1, false, false><<<dim3(NR / 128, 1), 128, 0, stream>>>(updg, rel_w, rel_b, nullptr, hbuf, NR, CC, RTOT * CC);
    // 7. x1 = x + g1 @ proj_w + proj_b   (into vbuf)
    gemm_kernel<0, true, false><<<dim3(NR / 128, 1), 128, 0, stream>>>(hbuf, proj_w, proj_b, x, vbuf, NR, CC, CC);
    // 8. h2 = LN2(x1)  (into hbuf)
    ln_kernel<<<(NR + 3) / 4, 256, 0, stream>>>(vbuf, n2g, n2b, hbuf, NR);
    // 9. hid = gelu(h2 @ fc1_w + fc1_b)  (into updg buffer)
    gemm_kernel<1, false, false><<<dim3(NR / 128, FFN / 96), 128, 0, stream>>>(hbuf, fc1_w, fc1_b, nullptr, updg, NR, FFN, CC);
    // 10. out = x1 + hid @ fc2_w + fc2_b
    gemm_kernel<0, true, false><<<dim3(NR / 128, 1), 128, 0, stream>>>(updg, fc2_w, fc2_b, vbuf, out, NR, CC, FFN);
}

// Round 5
// 451.486 us; speedup vs baseline: 2.1206x; 2.1206x over previous
//
#include <hip/hip_runtime.h>
#include <hip/hip_bf16.h>
#include <math.h>

// Problem constants (from reference file)
#define BB 16
#define LL 3136
#define CC 96
#define HH 56
#define WW 56
#define RR 3
#define RTOT 5
#define EE 131072
#define NR (BB*LL)            // 50176 rows
#define NSEG (LL*RR)          // 9408 segments
#define FFN 384

typedef __attribute__((ext_vector_type(8))) short bf16x8;
typedef __attribute__((ext_vector_type(4))) float f32x4;
typedef __attribute__((ext_vector_type(8))) unsigned short u16x8;

// ---- bf16 split helpers (RNE) ----
__device__ __forceinline__ unsigned short f2bf(float f) {
    unsigned u = __builtin_bit_cast(unsigned, f);
    unsigned r = u + 0x7FFF + ((u >> 16) & 1);
    return (unsigned short)(r >> 16);
}
__device__ __forceinline__ float bf2f(unsigned short h) {
    unsigned u = ((unsigned)h) << 16;
    return __builtin_bit_cast(float, u);
}

__device__ __forceinline__ float gelu_exact(float v) {
    return 0.5f * v * (1.0f + erff(v * 0.70710678118654752440f));
}

// ---------------- LayerNorm: one wave per row (96 elems) ----------------
__global__ __launch_bounds__(256) void ln_kernel(const float* __restrict__ x,
                                                 const float* __restrict__ g,
                                                 const float* __restrict__ bta,
                                                 float* __restrict__ out, int nrows)
{
    int wave = threadIdx.x >> 6;
    int lane = threadIdx.x & 63;
    int row  = blockIdx.x * 4 + wave;
    if (row >= nrows) return;
    const float* xr = x + (size_t)row * CC;
    float v0 = xr[lane];
    float v1 = (lane < 32) ? xr[64 + lane] : 0.f;
    float s = v0 + v1;
    #pragma unroll
    for (int off = 32; off; off >>= 1) s += __shfl_xor(s, off);
    float mean = s * (1.f / 96.f);
    float d0 = v0 - mean;
    float d1 = (lane < 32) ? (v1 - mean) : 0.f;
    float q = d0 * d0 + d1 * d1;
    #pragma unroll
    for (int off = 32; off; off >>= 1) q += __shfl_xor(q, off);
    float rstd = rsqrtf(q * (1.f / 96.f) + 1e-5f);
    out[(size_t)row * CC + lane] = d0 * rstd * g[lane] + bta[lane];
    if (lane < 32)
        out[(size_t)row * CC + 64 + lane] = d1 * rstd * g[64 + lane] + bta[64 + lane];
}

// ---------------- Weight pre-split: fp32 [K][N] -> bf16 hi/lo [N][K] ----------------
// Segments: value(96x96)@0, rel(480x96)@9216, proj(96x96)@55296,
//           fc1(96x384)@64512, fc2(384x96)@101376; total 138240.
#define SPL_TOT 138240
__global__ __launch_bounds__(256) void prep_split(const float* __restrict__ vw,
                                                  const float* __restrict__ rw,
                                                  const float* __restrict__ pw,
                                                  const float* __restrict__ f1w,
                                                  const float* __restrict__ f2w,
                                                  unsigned short* __restrict__ bhi,
                                                  unsigned short* __restrict__ blo)
{
    int t = blockIdx.x * 256 + threadIdx.x;
    if (t >= SPL_TOT) return;
    const float* src; int K, N, local;
    if (t < 9216)        { src = vw;  K = 96;  N = 96;  local = t; }
    else if (t < 55296)  { src = rw;  K = 480; N = 96;  local = t - 9216; }
    else if (t < 64512)  { src = pw;  K = 96;  N = 96;  local = t - 55296; }
    else if (t < 101376) { src = f1w; K = 96;  N = 384; local = t - 64512; }
    else                 { src = f2w; K = 384; N = 96;  local = t - 101376; }
    int n = local / K, k = local - n * K;
    float f = src[(size_t)k * N + n];
    unsigned short h = f2bf(f);
    unsigned short l = f2bf(f - bf2f(h));
    bhi[t] = h;     // [n][k] layout within segment (local = n*K + k)
    blo[t] = l;
}

// ---------------- MFMA GEMM with fp32-accurate bf16 split ----------------
// Block: 64 rows x 96 cols, 256 threads = 4 waves in 2(M)x2(N) grid;
// wave tile 32x48 = 2 m-tiles x 3 n-tiles of 16x16. K-chunks of 32.
// A (fp32 [M][K]) split on the fly into LDS; B pre-split bf16 [N][K] hi/lo.
// D = Ah*Bh + Ah*Bl + Al*Bh (fp32 accum) — ~2^-17 relative error.
template<int ACT, bool RES, bool PERM>
__global__ __launch_bounds__(256) void gemm_mfma(const float* __restrict__ A,
                                                 const unsigned short* __restrict__ Bhi,
                                                 const unsigned short* __restrict__ Blo,
                                                 const float* __restrict__ bias,
                                                 const float* __restrict__ res,
                                                 float* __restrict__ out,
                                                 int M, int N, int K)
{
    __shared__ unsigned short AsH[64 * 32], AsL[64 * 32];
    __shared__ unsigned short BsH[96 * 32], BsL[96 * 32];
    const int tid  = threadIdx.x;
    const int bm   = blockIdx.x * 64;
    const int bn   = blockIdx.y * 96;
    const int lane = tid & 63;
    const int w    = tid >> 6;
    const int wm   = w >> 1, wn = w & 1;
    const int r16  = lane & 15, q = lane >> 4;

    f32x4 acc[2][3];
    #pragma unroll
    for (int mt = 0; mt < 2; mt++)
        #pragma unroll
        for (int nt = 0; nt < 3; nt++) acc[mt][nt] = (f32x4)0.f;

    const int arow = tid >> 2;           // A staging: row 0..63
    const int akq  = (tid & 3) * 8;      // k offset 0,8,16,24
    const int bn_  = tid >> 1;           // B staging: n 0..95 (tid<192)
    const int bh_  = (tid & 1) * 16;     // k offset 0,16

    for (int kc = 0; kc < K; kc += 32) {
        __syncthreads();
        // ---- stage A (fp32 -> hi/lo bf16) ----
        {
            const float* ap = A + (size_t)(bm + arow) * K + kc + akq;
            float4 f0 = *(const float4*)ap;
            float4 f1 = *(const float4*)(ap + 4);
            float ff[8] = {f0.x, f0.y, f0.z, f0.w, f1.x, f1.y, f1.z, f1.w};
            u16x8 h8, l8;
            #pragma unroll
            for (int j = 0; j < 8; j++) {
                unsigned short h = f2bf(ff[j]);
                h8[j] = h;
                l8[j] = f2bf(ff[j] - bf2f(h));
            }
            *(u16x8*)&AsH[arow * 32 + akq] = h8;
            *(u16x8*)&AsL[arow * 32 + akq] = l8;
        }
        // ---- stage B (pre-split bf16, [N][K] n-major) ----
        if (tid < 192) {
            const unsigned short* bph = Bhi + (size_t)(bn + bn_) * K + kc + bh_;
            const unsigned short* bpl = Blo + (size_t)(bn + bn_) * K + kc + bh_;
            u16x8 h0 = *(const u16x8*)bph;
            u16x8 h1 = *(const u16x8*)(bph + 8);
            u16x8 l0 = *(const u16x8*)bpl;
            u16x8 l1 = *(const u16x8*)(bpl + 8);
            *(u16x8*)&BsH[bn_ * 32 + bh_ + 0] = h0;
            *(u16x8*)&BsH[bn_ * 32 + bh_ + 8] = h1;
            *(u16x8*)&BsL[bn_ * 32 + bh_ + 0] = l0;
            *(u16x8*)&BsL[bn_ * 32 + bh_ + 8] = l1;
        }
        __syncthreads();
        // ---- fragments ----
        bf16x8 aH[2], aL[2], bH[3], bL[3];
        #pragma unroll
        for (int mt = 0; mt < 2; mt++) {
            int rbase = (wm * 32 + mt * 16 + r16) * 32 + q * 8;
            aH[mt] = *(const bf16x8*)&AsH[rbase];
            aL[mt] = *(const bf16x8*)&AsL[rbase];
        }
        #pragma unroll
        for (int nt = 0; nt < 3; nt++) {
            int cbase = (wn * 48 + nt * 16 + r16) * 32 + q * 8;
            bH[nt] = *(const bf16x8*)&BsH[cbase];
            bL[nt] = *(const bf16x8*)&BsL[cbase];
        }
        // ---- 18 MFMAs ----
        #pragma unroll
        for (int mt = 0; mt < 2; mt++)
            #pragma unroll
            for (int nt = 0; nt < 3; nt++) {
                acc[mt][nt] = __builtin_amdgcn_mfma_f32_16x16x32_bf16(aH[mt], bH[nt], acc[mt][nt], 0, 0, 0);
                acc[mt][nt] = __builtin_amdgcn_mfma_f32_16x16x32_bf16(aH[mt], bL[nt], acc[mt][nt], 0, 0, 0);
                acc[mt][nt] = __builtin_amdgcn_mfma_f32_16x16x32_bf16(aL[mt], bH[nt], acc[mt][nt], 0, 0, 0);
            }
    }

    // ---- epilogue: D[row=(q*4+r)][col=r16] per 16x16 tile ----
    #pragma unroll
    for (int mt = 0; mt < 2; mt++) {
        #pragma unroll
        for (int nt = 0; nt < 3; nt++) {
            int col = bn + wn * 48 + nt * 16 + r16;
            float bv = bias[col];
            #pragma unroll
            for (int r = 0; r < 4; r++) {
                int row = bm + wm * 32 + mt * 16 + q * 4 + r;
                float val = acc[mt][nt][r] + bv;
                if (ACT == 1) val = gelu_exact(val);
                if (RES) val += res[(size_t)row * N + col];
                size_t orow;
                if (PERM) {
                    int b = row / LL;
                    int l = row - b * LL;
                    orow = (size_t)l * BB + b;
                } else {
                    orow = (size_t)row;
                }
                out[orow * N + col] = val;
            }
        }
    }
}

// ---------------- Gate: wave per row, 5 shuffle-reduced dots ----------------
__global__ __launch_bounds__(256) void gate_kernel(const float* __restrict__ h,
                                                   const float* __restrict__ gw,
                                                   const float* __restrict__ gb,
                                                   float* __restrict__ gate)
{
    int wave = threadIdx.x >> 6;
    int lane = threadIdx.x & 63;
    int row  = blockIdx.x * 4 + wave;
    if (row >= NR) return;
    const float* hr = h + (size_t)row * CC;
    float v0 = hr[lane];
    float v1 = (lane < 32) ? hr[64 + lane] : 0.f;
    #pragma unroll
    for (int r = 0; r < RTOT; r++) {
        float s = v0 * gw[lane * RTOT + r];
        if (lane < 32) s += v1 * gw[(64 + lane) * RTOT + r];
        #pragma unroll
        for (int off = 32; off; off >>= 1) s += __shfl_xor(s, off);
        if (lane == r) gate[(size_t)row * RTOT + r] = 1.f / (1.f + expf(-(s + gb[r])));
    }
}

// ---------------- CSR build ----------------
__global__ void hist_kernel(const int* __restrict__ ei, const int* __restrict__ et,
                            int* __restrict__ cnt)
{
    int e = blockIdx.x * 256 + threadIdx.x;
    if (e >= EE) return;
    int dst = ei[EE + e];
    int r   = et[e];
    atomicAdd(&cnt[dst * RR + r], 1);
}

// 1024-thread hierarchical block scan over NSEG=9408
__global__ __launch_bounds__(1024) void scan_kernel(const int* __restrict__ cnt,
                                                    int* __restrict__ colptr,
                                                    float* __restrict__ invcnt)
{
    __shared__ int wsum[16];
    int tid = threadIdx.x, wid = tid >> 6, lane = tid & 63;
    int carry = 0;
    for (int base = 0; base < NSEG; base += 1024) {
        int idx = base + tid;
        int v = (idx < NSEG) ? cnt[idx] : 0;
        if (idx < NSEG) invcnt[idx] = 1.f / (float)max(v, 1);
        int sc = v;
        #pragma unroll
        for (int off = 1; off < 64; off <<= 1) {
            int o = __shfl_up(sc, off);
            if (lane >= off) sc += o;
        }
        if (lane == 63) wsum[wid] = sc;
        __syncthreads();
        if (wid == 0) {
            int w = (lane < 16) ? wsum[lane] : 0;
            #pragma unroll
            for (int off = 1; off < 16; off <<= 1) {
                int o = __shfl_up(w, off);
                if (lane >= off) w += o;
            }
            if (lane < 16) wsum[lane] = w;
        }
        __syncthreads();
        int woff = (wid > 0) ? wsum[wid - 1] : 0;
        if (idx < NSEG) colptr[idx] = carry + woff + sc - v;   // exclusive
        carry += wsum[15];
        __syncthreads();
    }
    if (tid == 0) colptr[NSEG] = carry;
}

__global__ void scatter_kernel(const int* __restrict__ ei, const int* __restrict__ et,
                               const int* __restrict__ colptr, int* __restrict__ fill,
                               int* __restrict__ esorted)
{
    int e = blockIdx.x * 256 + threadIdx.x;
    if (e >= EE) return;
    int src = ei[e];
    int dst = ei[EE + e];
    int seg = dst * RR + et[e];
    int pos = colptr[seg] + atomicAdd(&fill[seg], 1);
    esorted[pos] = src;
}

// ---------------- Aggregation + depthwise convs + gating → updg [B,L,480] ----------------
// v is in [L,B,C] layout (vperm). One block per l, 96 threads (channel),
// each thread keeps all 16 batch accumulators in registers.
__global__ __launch_bounds__(96) void aggconv_kernel(const float* __restrict__ vp,
                               const float* __restrict__ gate,
                               const int* __restrict__ colptr, const int* __restrict__ esorted,
                               const float* __restrict__ invcnt,
                               const float* __restrict__ k3, const float* __restrict__ b3,
                               const float* __restrict__ k5, const float* __restrict__ b5,
                               float* __restrict__ updg)
{
    int l = blockIdx.x;
    int c = threadIdx.x;     // channel 0..95
    __shared__ float gs[BB][RTOT];
    if (c < BB * RTOT) {
        int b = c / RTOT, r = c - b * RTOT;
        gs[b][r] = gate[((size_t)b * LL + l) * RTOT + r];
    }
    __syncthreads();

    // graph relations: mean-aggregate with batch-register blocking
    #pragma unroll
    for (int r = 0; r < RR; r++) {
        int s0 = colptr[l * RR + r], s1 = colptr[l * RR + r + 1];
        float acc[BB];
        #pragma unroll
        for (int b = 0; b < BB; b++) acc[b] = 0.f;
        int src = (s0 < s1) ? esorted[s0] : 0;
        for (int e = s0; e < s1; e++) {
            int nsrc = (e + 1 < s1) ? esorted[e + 1] : 0;
            const float* p = vp + (size_t)src * (BB * CC) + c;
            #pragma unroll
            for (int b = 0; b < BB; b++) acc[b] += p[b * CC];
            src = nsrc;
        }
        float inv = invcnt[l * RR + r];
        #pragma unroll
        for (int b = 0; b < BB; b++)
            updg[((size_t)b * LL + l) * (RTOT * CC) + r * CC + c] = acc[b] * inv * gs[b][r];
    }

    // context: 5x5 depthwise with fused 3x3 (3x3 taps are a subset)
    int h0 = l / WW, w0 = l - (l / WW) * WW;
    float a3[BB], a5[BB];
    float bb3 = b3[c], bb5 = b5[c];
    #pragma unroll
    for (int b = 0; b < BB; b++) { a3[b] = bb3; a5[b] = bb5; }
    #pragma unroll
    for (int kh = -2; kh <= 2; kh++) {
        int hh = h0 + kh; if (hh < 0 || hh >= HH) continue;
        #pragma unroll
        for (int kw = -2; kw <= 2; kw++) {
            int ww = w0 + kw; if (ww < 0 || ww >= WW) continue;
            float w5 = k5[c * 25 + (kh + 2) * 5 + (kw + 2)];
            bool in3 = (kh >= -1 && kh <= 1 && kw >= -1 && kw <= 1);
            float w3 = in3 ? k3[c * 9 + (kh + 1) * 3 + (kw + 1)] : 0.f;
            const float* p = vp + (size_t)(hh * WW + ww) * (BB * CC) + c;
            #pragma unroll
            for (int b = 0; b < BB; b++) {
                float t = p[b * CC];
                a5[b] += t * w5;
                a3[b] += t * w3;
            }
        }
    }
    #pragma unroll
    for (int b = 0; b < BB; b++) {
        size_t ob = ((size_t)b * LL + l) * (RTOT * CC);
        updg[ob + 3 * CC + c] = a3[b] * gs[b][3];
        updg[ob + 4 * CC + c] = a5[b] * gs[b][4];
    }
}

// ---------------- launch ----------------
extern "C" void kernel_launch(void* const* d_in, const int* in_sizes, int n_in,
                              void* d_out, int out_size, void* d_ws, size_t ws_size,
                              hipStream_t stream)
{
    const float* x       = (const float*)d_in[0];
    const int*   ei      = (const int*)d_in[1];
    const int*   et      = (const int*)d_in[2];
    // d_in[3], d_in[4] = H, W (hardcoded 56)
    const float* n1g     = (const float*)d_in[5];
    const float* n1b     = (const float*)d_in[6];
    const float* value_w = (const float*)d_in[7];
    const float* value_b = (const float*)d_in[8];
    const float* gate_w  = (const float*)d_in[9];
    const float* gate_b  = (const float*)d_in[10];
    const float* k3      = (const float*)d_in[11];
    const float* b3      = (const float*)d_in[12];
    const float* k5      = (const float*)d_in[13];
    const float* b5      = (const float*)d_in[14];
    const float* rel_w   = (const float*)d_in[15];
    const float* rel_b   = (const float*)d_in[16];
    const float* proj_w  = (const float*)d_in[17];
    const float* proj_b  = (const float*)d_in[18];
    const float* n2g     = (const float*)d_in[19];
    const float* n2b     = (const float*)d_in[20];
    const float* fc1_w   = (const float*)d_in[21];
    const float* fc1_b   = (const float*)d_in[22];
    const float* fc2_w   = (const float*)d_in[23];
    const float* fc2_b   = (const float*)d_in[24];
    float* out = (float*)d_out;

    // workspace layout (floats)
    float* w = (float*)d_ws;
    const size_t SZ_ROW = (size_t)NR * CC;            // 4,816,896
    float* hbuf   = w;                                 // h, later g1, later h2
    float* vbuf   = hbuf + SZ_ROW;                     // vperm [L,B,C], later x1 [B,L,C]
    float* gateb  = vbuf + SZ_ROW;                     // [NR,5]
    float* updg   = gateb + (size_t)NR * RTOT;         // [NR,480], later ffn hidden [NR,384]
    int*   ibase  = (int*)(updg + (size_t)NR * RTOT * CC);
    int*   cnt     = ibase;                            // [NSEG]
    int*   colptr  = cnt + NSEG;                       // [NSEG+1]
    int*   fill    = colptr + NSEG + 1;                // [NSEG]
    int*   esorted = fill + NSEG;                      // [E]
    float* invcnt  = (float*)(esorted + EE);           // [NSEG]
    unsigned short* bhi = (unsigned short*)(invcnt + NSEG);  // [138240]
    unsigned short* blo = bhi + SPL_TOT;                     // [138240]

    // zero the counters
    hipMemsetAsync(cnt, 0, NSEG * sizeof(int), stream);
    hipMemsetAsync(fill, 0, NSEG * sizeof(int), stream);

    // 0. weight pre-split (fp32 [K][N] -> bf16 hi/lo [N][K])
    prep_split<<<(SPL_TOT + 255) / 256, 256, 0, stream>>>(value_w, rel_w, proj_w, fc1_w, fc2_w, bhi, blo);
    // 1. LN1
    ln_kernel<<<NR / 4, 256, 0, stream>>>(x, n1g, n1b, hbuf, NR);
    // 2. vperm[l,b,:] = (h @ value_w + value_b)[b*LL+l]  (PERM write)
    gemm_mfma<0, false, true><<<dim3(NR / 64, 1), 256, 0, stream>>>(hbuf, bhi + 0, blo + 0, value_b, nullptr, vbuf, NR, 96, 96);
    // 3. gates
    gate_kernel<<<NR / 4, 256, 0, stream>>>(hbuf, gate_w, gate_b, gateb);
    // 4. CSR build
    hist_kernel<<<EE / 256, 256, 0, stream>>>(ei, et, cnt);
    scan_kernel<<<1, 1024, 0, stream>>>(cnt, colptr, invcnt);
    scatter_kernel<<<EE / 256, 256, 0, stream>>>(ei, et, colptr, fill, esorted);
    // 5. aggregation + convs + gating (batch-register blocked)
    aggconv_kernel<<<dim3(LL), 96, 0, stream>>>(vbuf, gateb, colptr, esorted, invcnt,
                                                k3, b3, k5, b5, updg);
    // 6. g1 = gelu(updg @ rel_w + rel_b)  (into hbuf)
    gemm_mfma<1, false, false><<<dim3(NR / 64, 1), 256, 0, stream>>>(updg, bhi + 9216, blo + 9216, rel_b, nullptr, hbuf, NR, 96, 480);
    // 7. x1 = x + g1 @ proj_w + proj_b   (into vbuf)
    gemm_mfma<0, true, false><<<dim3(NR / 64, 1), 256, 0, stream>>>(hbuf, bhi + 55296, blo + 55296, proj_b, x, vbuf, NR, 96, 96);
    // 8. h2 = LN2(x1)  (into hbuf)
    ln_kernel<<<NR / 4, 256, 0, stream>>>(vbuf, n2g, n2b, hbuf, NR);
    // 9. hid = gelu(h2 @ fc1_w + fc1_b)  (into updg buffer)
    gemm_mfma<1, false, false><<<dim3(NR / 64, 4), 256, 0, stream>>>(hbuf, bhi + 64512, blo + 64512, fc1_b, nullptr, updg, NR, 384, 96);
    // 10. out = x1 + hid @ fc2_w + fc2_b
    gemm_mfma<0, true, false><<<dim3(NR / 64, 1), 256, 0, stream>>>(updg, bhi + 101376, blo + 101376, fc2_b, vbuf, out, NR, 96, 384);
}

// Round 12
// 379.072 us; speedup vs baseline: 2.5257x; 1.1910x over previous
//
#include <hip/hip_runtime.h>
#include <hip/hip_bf16.h>
#include <math.h>

// Problem constants (from reference file)
#define BB 16
#define LL 3136
#define CC 96
#define HH 56
#define WW 56
#define RR 3
#define RTOT 5
#define EE 131072
#define NR (BB*LL)            // 50176 rows
#define NSEG (LL*RR)          // 9408 segments
#define FFN 384

typedef __attribute__((ext_vector_type(8))) short bf16x8;
typedef __attribute__((ext_vector_type(4))) float f32x4;
typedef __attribute__((ext_vector_type(8))) unsigned short u16x8;

// ---- bf16 helpers (RNE) ----
__device__ __forceinline__ unsigned short f2bf(float f) {
    unsigned u = __builtin_bit_cast(unsigned, f);
    unsigned r = u + 0x7FFF + ((u >> 16) & 1);
    return (unsigned short)(r >> 16);
}
__device__ __forceinline__ float bf2f(unsigned short h) {
    unsigned u = ((unsigned)h) << 16;
    return __builtin_bit_cast(float, u);
}

__device__ __forceinline__ float gelu_exact(float v) {
    return 0.5f * v * (1.0f + erff(v * 0.70710678118654752440f));
}

// ---------------- LayerNorm: one wave per row (96 elems) ----------------
__global__ __launch_bounds__(256) void ln_kernel(const float* __restrict__ x,
                                                 const float* __restrict__ g,
                                                 const float* __restrict__ bta,
                                                 float* __restrict__ out, int nrows)
{
    int wave = threadIdx.x >> 6;
    int lane = threadIdx.x & 63;
    int row  = blockIdx.x * 4 + wave;
    if (row >= nrows) return;
    const float* xr = x + (size_t)row * CC;
    float v0 = xr[lane];
    float v1 = (lane < 32) ? xr[64 + lane] : 0.f;
    float s = v0 + v1;
    #pragma unroll
    for (int off = 32; off; off >>= 1) s += __shfl_xor(s, off);
    float mean = s * (1.f / 96.f);
    float d0 = v0 - mean;
    float d1 = (lane < 32) ? (v1 - mean) : 0.f;
    float q = d0 * d0 + d1 * d1;
    #pragma unroll
    for (int off = 32; off; off >>= 1) q += __shfl_xor(q, off);
    float rstd = rsqrtf(q * (1.f / 96.f) + 1e-5f);
    out[(size_t)row * CC + lane] = d0 * rstd * g[lane] + bta[lane];
    if (lane < 32)
        out[(size_t)row * CC + 64 + lane] = d1 * rstd * g[64 + lane] + bta[64 + lane];
}

// ---------------- Weight pre-split: fp32 [K][N] -> bf16 hi/lo [N][K] ----------------
// Segments: value(96x96)@0, rel(480x96)@9216, proj(96x96)@55296,
//           fc1(96x384)@64512, fc2(384x96)@101376; total 138240.
#define SPL_TOT 138240
__global__ __launch_bounds__(256) void prep_split(const float* __restrict__ vw,
                                                  const float* __restrict__ rw,
                                                  const float* __restrict__ pw,
                                                  const float* __restrict__ f1w,
                                                  const float* __restrict__ f2w,
                                                  unsigned short* __restrict__ bhi,
                                                  unsigned short* __restrict__ blo)
{
    int t = blockIdx.x * 256 + threadIdx.x;
    if (t >= SPL_TOT) return;
    const float* src; int K, N, local;
    if (t < 9216)        { src = vw;  K = 96;  N = 96;  local = t; }
    else if (t < 55296)  { src = rw;  K = 480; N = 96;  local = t - 9216; }
    else if (t < 64512)  { src = pw;  K = 96;  N = 96;  local = t - 55296; }
    else if (t < 101376) { src = f1w; K = 96;  N = 384; local = t - 64512; }
    else                 { src = f2w; K = 384; N = 96;  local = t - 101376; }
    int n = local / K, k = local - n * K;
    float f = src[(size_t)k * N + n];
    unsigned short h = f2bf(f);
    unsigned short l = f2bf(f - bf2f(h));
    bhi[t] = h;     // [n][k] layout within segment (local = n*K + k)
    blo[t] = l;
}

// ---------------- Conv-weight transpose: [C][tap] -> [tap][C] ----------------
__global__ __launch_bounds__(256) void prep_convw(const float* __restrict__ k3,
                                                  const float* __restrict__ k5,
                                                  float* __restrict__ k3t,
                                                  float* __restrict__ k5t)
{
    int t = blockIdx.x * 256 + threadIdx.x;
    if (t < 864) {                       // 96*9
        int c = t / 9, tap = t - c * 9;
        k3t[tap * 96 + c] = k3[t];
    } else if (t < 864 + 2400) {         // 96*25
        int u = t - 864;
        int c = u / 25, tap = u - c * 25;
        k5t[tap * 96 + c] = k5[u];
    }
}

// ---------------- MFMA GEMM with fp32-accurate bf16 split ----------------
// Block: 64 rows x 96 cols, 256 threads = 4 waves in 2(M)x2(N) grid;
// wave tile 32x48 = 2 m-tiles x 3 n-tiles of 16x16. K-chunks of 32.
// ABF16=false: A fp32 [M][K], split on the fly, D = Ah*Bh + Ah*Bl + Al*Bh.
// ABF16=true:  A bf16 [M][K], D = A*Bh + A*Bl.
// OUTBF16: store output as bf16 (ushort). PERM: row (b*LL+l) -> (l*BB+b).
template<int ACT, bool RES, bool PERM, bool ABF16, bool OUTBF16>
__global__ __launch_bounds__(256) void gemm_mfma(const void* __restrict__ Ain,
                                                 const unsigned short* __restrict__ Bhi,
                                                 const unsigned short* __restrict__ Blo,
                                                 const float* __restrict__ bias,
                                                 const float* __restrict__ res,
                                                 void* __restrict__ outv,
                                                 int M, int N, int K)
{
    __shared__ unsigned short AsH[64 * 32];
    __shared__ unsigned short AsL[ABF16 ? 8 : 64 * 32];
    __shared__ unsigned short BsH[96 * 32], BsL[96 * 32];
    const int tid  = threadIdx.x;
    const int bm   = blockIdx.x * 64;
    const int bn   = blockIdx.y * 96;
    const int lane = tid & 63;
    const int w    = tid >> 6;
    const int wm   = w >> 1, wn = w & 1;
    const int r16  = lane & 15, q = lane >> 4;

    f32x4 acc[2][3];
    #pragma unroll
    for (int mt = 0; mt < 2; mt++)
        #pragma unroll
        for (int nt = 0; nt < 3; nt++) acc[mt][nt] = (f32x4)0.f;

    const int arow = tid >> 2;           // A staging: row 0..63
    const int akq  = (tid & 3) * 8;      // k offset 0,8,16,24
    const int bn_  = tid >> 1;           // B staging: n 0..95 (tid<192)
    const int bh_  = (tid & 1) * 16;     // k offset 0,16

    for (int kc = 0; kc < K; kc += 32) {
        __syncthreads();
        // ---- stage A ----
        if constexpr (ABF16) {
            const unsigned short* Ab = (const unsigned short*)Ain;
            u16x8 h8 = *(const u16x8*)&Ab[(size_t)(bm + arow) * K + kc + akq];
            *(u16x8*)&AsH[arow * 32 + akq] = h8;
        } else {
            const float* A = (const float*)Ain;
            const float* ap = A + (size_t)(bm + arow) * K + kc + akq;
            float4 f0 = *(const float4*)ap;
            float4 f1 = *(const float4*)(ap + 4);
            float ff[8] = {f0.x, f0.y, f0.z, f0.w, f1.x, f1.y, f1.z, f1.w};
            u16x8 h8, l8;
            #pragma unroll
            for (int j = 0; j < 8; j++) {
                unsigned short h = f2bf(ff[j]);
                h8[j] = h;
                l8[j] = f2bf(ff[j] - bf2f(h));
            }
            *(u16x8*)&AsH[arow * 32 + akq] = h8;
            *(u16x8*)&AsL[arow * 32 + akq] = l8;
        }
        // ---- stage B (pre-split bf16, [N][K] n-major) ----
        if (tid < 192) {
            const unsigned short* bph = Bhi + (size_t)(bn + bn_) * K + kc + bh_;
            const unsigned short* bpl = Blo + (size_t)(bn + bn_) * K + kc + bh_;
            u16x8 h0 = *(const u16x8*)bph;
            u16x8 h1 = *(const u16x8*)(bph + 8);
            u16x8 l0 = *(const u16x8*)bpl;
            u16x8 l1 = *(const u16x8*)(bpl + 8);
            *(u16x8*)&BsH[bn_ * 32 + bh_ + 0] = h0;
            *(u16x8*)&BsH[bn_ * 32 + bh_ + 8] = h1;
            *(u16x8*)&BsL[bn_ * 32 + bh_ + 0] = l0;
            *(u16x8*)&BsL[bn_ * 32 + bh_ + 8] = l1;
        }
        __syncthreads();
        // ---- fragments ----
        bf16x8 aH[2], aL[2], bH[3], bL[3];
        #pragma unroll
        for (int mt = 0; mt < 2; mt++) {
            int rbase = (wm * 32 + mt * 16 + r16) * 32 + q * 8;
            aH[mt] = *(const bf16x8*)&AsH[rbase];
            if constexpr (!ABF16) aL[mt] = *(const bf16x8*)&AsL[rbase];
        }
        #pragma unroll
        for (int nt = 0; nt < 3; nt++) {
            int cbase = (wn * 48 + nt * 16 + r16) * 32 + q * 8;
            bH[nt] = *(const bf16x8*)&BsH[cbase];
            bL[nt] = *(const bf16x8*)&BsL[cbase];
        }
        // ---- MFMAs ----
        #pragma unroll
        for (int mt = 0; mt < 2; mt++)
            #pragma unroll
            for (int nt = 0; nt < 3; nt++) {
                acc[mt][nt] = __builtin_amdgcn_mfma_f32_16x16x32_bf16(aH[mt], bH[nt], acc[mt][nt], 0, 0, 0);
                acc[mt][nt] = __builtin_amdgcn_mfma_f32_16x16x32_bf16(aH[mt], bL[nt], acc[mt][nt], 0, 0, 0);
                if constexpr (!ABF16)
                    acc[mt][nt] = __builtin_amdgcn_mfma_f32_16x16x32_bf16(aL[mt], bH[nt], acc[mt][nt], 0, 0, 0);
            }
    }

    // ---- epilogue: D[row=(q*4+r)][col=r16] per 16x16 tile ----
    #pragma unroll
    for (int mt = 0; mt < 2; mt++) {
        #pragma unroll
        for (int nt = 0; nt < 3; nt++) {
            int col = bn + wn * 48 + nt * 16 + r16;
            float bv = bias[col];
            #pragma unroll
            for (int r = 0; r < 4; r++) {
                int row = bm + wm * 32 + mt * 16 + q * 4 + r;
                float val = acc[mt][nt][r] + bv;
                if (ACT == 1) val = gelu_exact(val);
                if (RES) val += res[(size_t)row * N + col];
                size_t orow;
                if (PERM) {
                    int b = row / LL;
                    int l = row - b * LL;
                    orow = (size_t)l * BB + b;
                } else {
                    orow = (size_t)row;
                }
                if constexpr (OUTBF16)
                    ((unsigned short*)outv)[orow * N + col] = f2bf(val);
                else
                    ((float*)outv)[orow * N + col] = val;
            }
        }
    }
}

// ---------------- Gate: wave per row, 5 shuffle-reduced dots ----------------
__global__ __launch_bounds__(256) void gate_kernel(const float* __restrict__ h,
                                                   const float* __restrict__ gw,
                                                   const float* __restrict__ gb,
                                                   float* __restrict__ gate)
{
    int wave = threadIdx.x >> 6;
    int lane = threadIdx.x & 63;
    int row  = blockIdx.x * 4 + wave;
    if (row >= NR) return;
    const float* hr = h + (size_t)row * CC;
    float v0 = hr[lane];
    float v1 = (lane < 32) ? hr[64 + lane] : 0.f;
    #pragma unroll
    for (int r = 0; r < RTOT; r++) {
        float s = v0 * gw[lane * RTOT + r];
        if (lane < 32) s += v1 * gw[(64 + lane) * RTOT + r];
        #pragma unroll
        for (int off = 32; off; off >>= 1) s += __shfl_xor(s, off);
        if (lane == r) gate[(size_t)row * RTOT + r] = 1.f / (1.f + expf(-(s + gb[r])));
    }
}

// ---------------- CSR build ----------------
__global__ void hist_kernel(const int* __restrict__ ei, const int* __restrict__ et,
                            int* __restrict__ cnt)
{
    int e = blockIdx.x * 256 + threadIdx.x;
    if (e >= EE) return;
    int dst = ei[EE + e];
    int r   = et[e];
    atomicAdd(&cnt[dst * RR + r], 1);
}

// 1024-thread hierarchical block scan over NSEG=9408
__global__ __launch_bounds__(1024) void scan_kernel(const int* __restrict__ cnt,
                                                    int* __restrict__ colptr,
                                                    float* __restrict__ invcnt)
{
    __shared__ int wsum[16];
    int tid = threadIdx.x, wid = tid >> 6, lane = tid & 63;
    int carry = 0;
    for (int base = 0; base < NSEG; base += 1024) {
        int idx = base + tid;
        int v = (idx < NSEG) ? cnt[idx] : 0;
        if (idx < NSEG) invcnt[idx] = 1.f / (float)max(v, 1);
        int sc = v;
        #pragma unroll
        for (int off = 1; off < 64; off <<= 1) {
            int o = __shfl_up(sc, off);
            if (lane >= off) sc += o;
        }
        if (lane == 63) wsum[wid] = sc;
        __syncthreads();
        if (wid == 0) {
            int w = (lane < 16) ? wsum[lane] : 0;
            #pragma unroll
            for (int off = 1; off < 16; off <<= 1) {
                int o = __shfl_up(w, off);
                if (lane >= off) w += o;
            }
            if (lane < 16) wsum[lane] = w;
        }
        __syncthreads();
        int woff = (wid > 0) ? wsum[wid - 1] : 0;
        if (idx < NSEG) colptr[idx] = carry + woff + sc - v;   // exclusive
        carry += wsum[15];
        __syncthreads();
    }
    if (tid == 0) colptr[NSEG] = carry;
}

__global__ void scatter_kernel(const int* __restrict__ ei, const int* __restrict__ et,
                               const int* __restrict__ colptr, int* __restrict__ fill,
                               int* __restrict__ esorted)
{
    int e = blockIdx.x * 256 + threadIdx.x;
    if (e >= EE) return;
    int src = ei[e];
    int dst = ei[EE + e];
    int seg = dst * RR + et[e];
    int pos = colptr[seg] + atomicAdd(&fill[seg], 1);
    esorted[pos] = src;
}

// ---------------- Aggregation + depthwise convs + gating → updg bf16 [B,L,480] ----
// vp: bf16 [L][B][C]. 256 threads: thread = (b = t>>4, channel group g = t&15,
// channels g*6..g*6+5). Full waves, dword loads, fp32 accumulate, bf16 store.
__device__ __forceinline__ void unp6(const unsigned short* p, float* f) {
    unsigned u0 = *(const unsigned*)(p + 0);
    unsigned u1 = *(const unsigned*)(p + 2);
    unsigned u2 = *(const unsigned*)(p + 4);
    f[0] = bf2f((unsigned short)u0); f[1] = bf2f((unsigned short)(u0 >> 16));
    f[2] = bf2f((unsigned short)u1); f[3] = bf2f((unsigned short)(u1 >> 16));
    f[4] = bf2f((unsigned short)u2); f[5] = bf2f((unsigned short)(u2 >> 16));
}
__device__ __forceinline__ void pack6(unsigned short* p, const float* f) {
    unsigned u0 = (unsigned)f2bf(f[0]) | ((unsigned)f2bf(f[1]) << 16);
    unsigned u1 = (unsigned)f2bf(f[2]) | ((unsigned)f2bf(f[3]) << 16);
    unsigned u2 = (unsigned)f2bf(f[4]) | ((unsigned)f2bf(f[5]) << 16);
    *(unsigned*)(p + 0) = u0;
    *(unsigned*)(p + 2) = u1;
    *(unsigned*)(p + 4) = u2;
}

__global__ __launch_bounds__(256) void aggconv_kernel(
        const unsigned short* __restrict__ vp,
        const float* __restrict__ gate,
        const int* __restrict__ colptr, const int* __restrict__ esorted,
        const float* __restrict__ invcnt,
        const float* __restrict__ k3t, const float* __restrict__ b3,
        const float* __restrict__ k5t, const float* __restrict__ b5,
        unsigned short* __restrict__ updg)
{
    int l = blockIdx.x;
    int t = threadIdx.x;
    int b = t >> 4;          // 0..15
    int g = t & 15;          // channel group
    int ch = g * 6;

    float gs[RTOT];
    #pragma unroll
    for (int r = 0; r < RTOT; r++) gs[r] = gate[((size_t)b * LL + l) * RTOT + r];
    size_t ob = ((size_t)b * LL + l) * (RTOT * CC);

    // graph relations: mean-aggregate
    #pragma unroll
    for (int r = 0; r < RR; r++) {
        int s0 = colptr[l * RR + r], s1 = colptr[l * RR + r + 1];
        float acc[6] = {0.f, 0.f, 0.f, 0.f, 0.f, 0.f};
        int src = (s0 < s1) ? esorted[s0] : 0;
        for (int e = s0; e < s1; e++) {
            int nsrc = (e + 1 < s1) ? esorted[e + 1] : 0;
            float f[6];
            unp6(vp + ((size_t)src * BB + b) * CC + ch, f);
            #pragma unroll
            for (int j = 0; j < 6; j++) acc[j] += f[j];
            src = nsrc;
        }
        float sc = invcnt[l * RR + r] * gs[r];
        float o[6];
        #pragma unroll
        for (int j = 0; j < 6; j++) o[j] = acc[j] * sc;
        unsigned short ov[6];
        pack6(ov, o);   // temp pack to locals then store
        *(unsigned*)(updg + ob + r * CC + ch + 0) = *(unsigned*)(ov + 0);
        *(unsigned*)(updg + ob + r * CC + ch + 2) = *(unsigned*)(ov + 2);
        *(unsigned*)(updg + ob + r * CC + ch + 4) = *(unsigned*)(ov + 4);
    }

    // context: 5x5 depthwise with fused 3x3 (3x3 taps subset of 5x5 window)
    int h0 = l / WW, w0 = l - (l / WW) * WW;
    float a3[6], a5[6];
    #pragma unroll
    for (int j = 0; j < 6; j++) { a3[j] = b3[ch + j]; a5[j] = b5[ch + j]; }
    #pragma unroll
    for (int kh = -2; kh <= 2; kh++) {
        int hh = h0 + kh; if (hh < 0 || hh >= HH) continue;
        #pragma unroll
        for (int kw = -2; kw <= 2; kw++) {
            int ww = w0 + kw; if (ww < 0 || ww >= WW) continue;
            float f[6];
            unp6(vp + ((size_t)(hh * WW + ww) * BB + b) * CC + ch, f);
            int tap5 = (kh + 2) * 5 + (kw + 2);
            #pragma unroll
            for (int j = 0; j < 6; j++) a5[j] += f[j] * k5t[tap5 * CC + ch + j];
            if (kh >= -1 && kh <= 1 && kw >= -1 && kw <= 1) {
                int tap3 = (kh + 1) * 3 + (kw + 1);
                #pragma unroll
                for (int j = 0; j < 6; j++) a3[j] += f[j] * k3t[tap3 * CC + ch + j];
            }
        }
    }
    float o3[6], o5[6];
    #pragma unroll
    for (int j = 0; j < 6; j++) { o3[j] = a3[j] * gs[3]; o5[j] = a5[j] * gs[4]; }
    unsigned short v3[6], v5[6];
    pack6(v3, o3);
    pack6(v5, o5);
    *(unsigned*)(updg + ob + 3 * CC + ch + 0) = *(unsigned*)(v3 + 0);
    *(unsigned*)(updg + ob + 3 * CC + ch + 2) = *(unsigned*)(v3 + 2);
    *(unsigned*)(updg + ob + 3 * CC + ch + 4) = *(unsigned*)(v3 + 4);
    *(unsigned*)(updg + ob + 4 * CC + ch + 0) = *(unsigned*)(v5 + 0);
    *(unsigned*)(updg + ob + 4 * CC + ch + 2) = *(unsigned*)(v5 + 2);
    *(unsigned*)(updg + ob + 4 * CC + ch + 4) = *(unsigned*)(v5 + 4);
}

// ---------------- launch ----------------
extern "C" void kernel_launch(void* const* d_in, const int* in_sizes, int n_in,
                              void* d_out, int out_size, void* d_ws, size_t ws_size,
                              hipStream_t stream)
{
    const float* x       = (const float*)d_in[0];
    const int*   ei      = (const int*)d_in[1];
    const int*   et      = (const int*)d_in[2];
    // d_in[3], d_in[4] = H, W (hardcoded 56)
    const float* n1g     = (const float*)d_in[5];
    const float* n1b     = (const float*)d_in[6];
    const float* value_w = (const float*)d_in[7];
    const float* value_b = (const float*)d_in[8];
    const float* gate_w  = (const float*)d_in[9];
    const float* gate_b  = (const float*)d_in[10];
    const float* k3      = (const float*)d_in[11];
    const float* b3      = (const float*)d_in[12];
    const float* k5      = (const float*)d_in[13];
    const float* b5      = (const float*)d_in[14];
    const float* rel_w   = (const float*)d_in[15];
    const float* rel_b   = (const float*)d_in[16];
    const float* proj_w  = (const float*)d_in[17];
    const float* proj_b  = (const float*)d_in[18];
    const float* n2g     = (const float*)d_in[19];
    const float* n2b     = (const float*)d_in[20];
    const float* fc1_w   = (const float*)d_in[21];
    const float* fc1_b   = (const float*)d_in[22];
    const float* fc2_w   = (const float*)d_in[23];
    const float* fc2_b   = (const float*)d_in[24];
    float* out = (float*)d_out;

    // workspace layout (float extents kept; bf16 views carved inside)
    float* w = (float*)d_ws;
    const size_t SZ_ROW = (size_t)NR * CC;            // 4,816,896
    float* hbuf   = w;                                 // h (fp32), later g1_bf (bf16), later h2 (fp32)
    float* vbuf   = hbuf + SZ_ROW;                     // vp_bf (bf16 [L][B][C]), later x1 (fp32)
    float* gateb  = vbuf + SZ_ROW;                     // [NR,5]
    float* updg   = gateb + (size_t)NR * RTOT;         // updg_bf [NR,480] bf16, later hid_bf [NR,384] bf16
    int*   ibase  = (int*)(updg + (size_t)NR * RTOT * CC);
    int*   cnt     = ibase;                            // [NSEG]
    int*   colptr  = cnt + NSEG;                       // [NSEG+1]
    int*   fill    = colptr + NSEG + 1;                // [NSEG]
    int*   esorted = fill + NSEG;                      // [E]
    float* invcnt  = (float*)(esorted + EE);           // [NSEG]
    unsigned short* bhi = (unsigned short*)(invcnt + NSEG);  // [138240]
    unsigned short* blo = bhi + SPL_TOT;                     // [138240]
    float* k3t = (float*)(blo + SPL_TOT);              // [9*96]
    float* k5t = k3t + 864;                            // [25*96]

    unsigned short* vp_bf   = (unsigned short*)vbuf;
    unsigned short* g1_bf   = (unsigned short*)hbuf;
    unsigned short* updg_bf = (unsigned short*)updg;
    unsigned short* hid_bf  = (unsigned short*)updg;
    float* x1 = vbuf;

    // zero the counters
    hipMemsetAsync(cnt, 0, NSEG * sizeof(int), stream);
    hipMemsetAsync(fill, 0, NSEG * sizeof(int), stream);

    // 0. weight prep
    prep_split<<<(SPL_TOT + 255) / 256, 256, 0, stream>>>(value_w, rel_w, proj_w, fc1_w, fc2_w, bhi, blo);
    prep_convw<<<(864 + 2400 + 255) / 256, 256, 0, stream>>>(k3, k5, k3t, k5t);
    // 1. LN1: x -> h (fp32, hbuf)
    ln_kernel<<<NR / 4, 256, 0, stream>>>(x, n1g, n1b, hbuf, NR);
    // 2. vp_bf[l,b,:] = bf16(h @ value_w + value_b)  (PERM + OUTBF16)
    gemm_mfma<0, false, true, false, true><<<dim3(NR / 64, 1), 256, 0, stream>>>(hbuf, bhi + 0, blo + 0, value_b, nullptr, vp_bf, NR, 96, 96);
    // 3. gates
    gate_kernel<<<NR / 4, 256, 0, stream>>>(hbuf, gate_w, gate_b, gateb);
    // 4. CSR build
    hist_kernel<<<EE / 256, 256, 0, stream>>>(ei, et, cnt);
    scan_kernel<<<1, 1024, 0, stream>>>(cnt, colptr, invcnt);
    scatter_kernel<<<EE / 256, 256, 0, stream>>>(ei, et, colptr, fill, esorted);
    // 5. aggregation + convs + gating -> updg_bf
    aggconv_kernel<<<dim3(LL), 256, 0, stream>>>(vp_bf, gateb, colptr, esorted, invcnt,
                                                 k3t, b3, k5t, b5, updg_bf);
    // 6. g1_bf = bf16(gelu(updg @ rel_w + rel_b))  (ABF16 + OUTBF16, into hbuf region)
    gemm_mfma<1, false, false, true, true><<<dim3(NR / 64, 1), 256, 0, stream>>>(updg_bf, bhi + 9216, blo + 9216, rel_b, nullptr, g1_bf, NR, 96, 480);
    // 7. x1 = x + g1 @ proj_w + proj_b  (ABF16, fp32 out into vbuf)
    gemm_mfma<0, true, false, true, false><<<dim3(NR / 64, 1), 256, 0, stream>>>(g1_bf, bhi + 55296, blo + 55296, proj_b, x, x1, NR, 96, 96);
    // 8. h2 = LN2(x1)  (fp32, into hbuf)
    ln_kernel<<<NR / 4, 256, 0, stream>>>(x1, n2g, n2b, hbuf, NR);
    // 9. hid_bf = bf16(gelu(h2 @ fc1_w + fc1_b))  (OUTBF16, into updg region)
    gemm_mfma<1, false, false, false, true><<<dim3(NR / 64, 4), 256, 0, stream>>>(hbuf, bhi + 64512, blo + 64512, fc1_b, nullptr, hid_bf, NR, 384, 96);
    // 10. out = x1 + hid @ fc2_w + fc2_b  (ABF16, fp32 out)
    gemm_mfma<0, true, false, true, false><<<dim3(NR / 64, 1), 256, 0, stream>>>(hid_bf, bhi + 101376, blo + 101376, fc2_b, x1, out, NR, 96, 384);
}

// Round 13
// 364.855 us; speedup vs baseline: 2.6241x; 1.0390x over previous
//
#include <hip/hip_runtime.h>
#include <hip/hip_bf16.h>
#include <math.h>

// Problem constants (from reference file)
#define BB 16
#define LL 3136
#define CC 96
#define HH 56
#define WW 56
#define RR 3
#define RTOT 5
#define EE 131072
#define NR (BB*LL)            // 50176 rows
#define NSEG (LL*RR)          // 9408 segments
#define FFN 384

typedef __attribute__((ext_vector_type(8))) short bf16x8;
typedef __attribute__((ext_vector_type(4))) float f32x4;
typedef __attribute__((ext_vector_type(8))) unsigned short u16x8;

// ---- bf16 helpers (RNE) ----
__device__ __forceinline__ unsigned short f2bf(float f) {
    unsigned u = __builtin_bit_cast(unsigned, f);
    unsigned r = u + 0x7FFF + ((u >> 16) & 1);
    return (unsigned short)(r >> 16);
}
__device__ __forceinline__ float bf2f(unsigned short h) {
    unsigned u = ((unsigned)h) << 16;
    return __builtin_bit_cast(float, u);
}

__device__ __forceinline__ float gelu_exact(float v) {
    return 0.5f * v * (1.0f + erff(v * 0.70710678118654752440f));
}

// ---------------- LayerNorm (optionally fused gate): one wave per row ----------------
// GATE=true additionally computes gate[row][r] = sigmoid(dot(LN_out_row, gw[:,r]) + gb[r])
// using the in-register normalized row (saves a full 19.3 MB re-read kernel).
template<bool GATE>
__global__ __launch_bounds__(256) void ln_kernel(const float* __restrict__ x,
                                                 const float* __restrict__ g,
                                                 const float* __restrict__ bta,
                                                 float* __restrict__ out,
                                                 const float* __restrict__ gw,
                                                 const float* __restrict__ gb,
                                                 float* __restrict__ gate,
                                                 int nrows)
{
    int wave = threadIdx.x >> 6;
    int lane = threadIdx.x & 63;
    int row  = blockIdx.x * 4 + wave;
    if (row >= nrows) return;
    const float* xr = x + (size_t)row * CC;
    float v0 = xr[lane];
    float v1 = (lane < 32) ? xr[64 + lane] : 0.f;
    float s = v0 + v1;
    #pragma unroll
    for (int off = 32; off; off >>= 1) s += __shfl_xor(s, off);
    float mean = s * (1.f / 96.f);
    float d0 = v0 - mean;
    float d1 = (lane < 32) ? (v1 - mean) : 0.f;
    float q = d0 * d0 + d1 * d1;
    #pragma unroll
    for (int off = 32; off; off >>= 1) q += __shfl_xor(q, off);
    float rstd = rsqrtf(q * (1.f / 96.f) + 1e-5f);
    float o0 = d0 * rstd * g[lane] + bta[lane];
    float o1 = 0.f;
    if (lane < 32) o1 = d1 * rstd * g[64 + lane] + bta[64 + lane];
    out[(size_t)row * CC + lane] = o0;
    if (lane < 32) out[(size_t)row * CC + 64 + lane] = o1;
    if constexpr (GATE) {
        #pragma unroll
        for (int r = 0; r < RTOT; r++) {
            float sg = o0 * gw[lane * RTOT + r];
            if (lane < 32) sg += o1 * gw[(64 + lane) * RTOT + r];
            #pragma unroll
            for (int off = 32; off; off >>= 1) sg += __shfl_xor(sg, off);
            if (lane == r) gate[(size_t)row * RTOT + r] = 1.f / (1.f + expf(-(sg + gb[r])));
        }
    }
}

// ---------------- Weight pre-split: fp32 [K][N] -> bf16 hi/lo [N][K] ----------------
// Segments: value(96x96)@0, rel(480x96)@9216, proj(96x96)@55296,
//           fc1(96x384)@64512, fc2(384x96)@101376; total 138240.
#define SPL_TOT 138240
__global__ __launch_bounds__(256) void prep_split(const float* __restrict__ vw,
                                                  const float* __restrict__ rw,
                                                  const float* __restrict__ pw,
                                                  const float* __restrict__ f1w,
                                                  const float* __restrict__ f2w,
                                                  unsigned short* __restrict__ bhi,
                                                  unsigned short* __restrict__ blo)
{
    int t = blockIdx.x * 256 + threadIdx.x;
    if (t >= SPL_TOT) return;
    const float* src; int K, N, local;
    if (t < 9216)        { src = vw;  K = 96;  N = 96;  local = t; }
    else if (t < 55296)  { src = rw;  K = 480; N = 96;  local = t - 9216; }
    else if (t < 64512)  { src = pw;  K = 96;  N = 96;  local = t - 55296; }
    else if (t < 101376) { src = f1w; K = 96;  N = 384; local = t - 64512; }
    else                 { src = f2w; K = 384; N = 96;  local = t - 101376; }
    int n = local / K, k = local - n * K;
    float f = src[(size_t)k * N + n];
    unsigned short h = f2bf(f);
    unsigned short l = f2bf(f - bf2f(h));
    bhi[t] = h;     // [n][k] layout within segment (local = n*K + k)
    blo[t] = l;
}

// ---------------- Conv-weight transpose: [C][tap] -> [tap][C] ----------------
__global__ __launch_bounds__(256) void prep_convw(const float* __restrict__ k3,
                                                  const float* __restrict__ k5,
                                                  float* __restrict__ k3t,
                                                  float* __restrict__ k5t)
{
    int t = blockIdx.x * 256 + threadIdx.x;
    if (t < 864) {                       // 96*9
        int c = t / 9, tap = t - c * 9;
        k3t[tap * 96 + c] = k3[t];
    } else if (t < 864 + 2400) {         // 96*25
        int u = t - 864;
        int c = u / 25, tap = u - c * 25;
        k5t[tap * 96 + c] = k5[u];
    }
}

// ---------------- MFMA GEMM with fp32-accurate bf16 split ----------------
// Block: 64 rows x 96 cols, 256 threads = 4 waves in 2(M)x2(N) grid;
// wave tile 32x48 = 2 m-tiles x 3 n-tiles of 16x16. K-chunks of 32.
// ABF16=false: A fp32 [M][K], split on the fly, D = Ah*Bh + Ah*Bl + Al*Bh.
// ABF16=true:  A bf16 [M][K], D = A*Bh + A*Bl.
// OUTBF16: store output as bf16 (ushort). PERM: row (b*LL+l) -> (l*BB+b).
template<int ACT, bool RES, bool PERM, bool ABF16, bool OUTBF16>
__global__ __launch_bounds__(256) void gemm_mfma(const void* __restrict__ Ain,
                                                 const unsigned short* __restrict__ Bhi,
                                                 const unsigned short* __restrict__ Blo,
                                                 const float* __restrict__ bias,
                                                 const float* __restrict__ res,
                                                 void* __restrict__ outv,
                                                 int M, int N, int K)
{
    __shared__ unsigned short AsH[64 * 32];
    __shared__ unsigned short AsL[ABF16 ? 8 : 64 * 32];
    __shared__ unsigned short BsH[96 * 32], BsL[96 * 32];
    const int tid  = threadIdx.x;
    const int bm   = blockIdx.x * 64;
    const int bn   = blockIdx.y * 96;
    const int lane = tid & 63;
    const int w    = tid >> 6;
    const int wm   = w >> 1, wn = w & 1;
    const int r16  = lane & 15, q = lane >> 4;

    f32x4 acc[2][3];
    #pragma unroll
    for (int mt = 0; mt < 2; mt++)
        #pragma unroll
        for (int nt = 0; nt < 3; nt++) acc[mt][nt] = (f32x4)0.f;

    const int arow = tid >> 2;           // A staging: row 0..63
    const int akq  = (tid & 3) * 8;      // k offset 0,8,16,24
    const int bn_  = tid >> 1;           // B staging: n 0..95 (tid<192)
    const int bh_  = (tid & 1) * 16;     // k offset 0,16

    for (int kc = 0; kc < K; kc += 32) {
        __syncthreads();
        // ---- stage A ----
        if constexpr (ABF16) {
            const unsigned short* Ab = (const unsigned short*)Ain;
            u16x8 h8 = *(const u16x8*)&Ab[(size_t)(bm + arow) * K + kc + akq];
            *(u16x8*)&AsH[arow * 32 + akq] = h8;
        } else {
            const float* A = (const float*)Ain;
            const float* ap = A + (size_t)(bm + arow) * K + kc + akq;
            float4 f0 = *(const float4*)ap;
            float4 f1 = *(const float4*)(ap + 4);
            float ff[8] = {f0.x, f0.y, f0.z, f0.w, f1.x, f1.y, f1.z, f1.w};
            u16x8 h8, l8;
            #pragma unroll
            for (int j = 0; j < 8; j++) {
                unsigned short h = f2bf(ff[j]);
                h8[j] = h;
                l8[j] = f2bf(ff[j] - bf2f(h));
            }
            *(u16x8*)&AsH[arow * 32 + akq] = h8;
            *(u16x8*)&AsL[arow * 32 + akq] = l8;
        }
        // ---- stage B (pre-split bf16, [N][K] n-major) ----
        if (tid < 192) {
            const unsigned short* bph = Bhi + (size_t)(bn + bn_) * K + kc + bh_;
            const unsigned short* bpl = Blo + (size_t)(bn + bn_) * K + kc + bh_;
            u16x8 h0 = *(const u16x8*)bph;
            u16x8 h1 = *(const u16x8*)(bph + 8);
            u16x8 l0 = *(const u16x8*)bpl;
            u16x8 l1 = *(const u16x8*)(bpl + 8);
            *(u16x8*)&BsH[bn_ * 32 + bh_ + 0] = h0;
            *(u16x8*)&BsH[bn_ * 32 + bh_ + 8] = h1;
            *(u16x8*)&BsL[bn_ * 32 + bh_ + 0] = l0;
            *(u16x8*)&BsL[bn_ * 32 + bh_ + 8] = l1;
        }
        __syncthreads();
        // ---- fragments ----
        bf16x8 aH[2], aL[2], bH[3], bL[3];
        #pragma unroll
        for (int mt = 0; mt < 2; mt++) {
            int rbase = (wm * 32 + mt * 16 + r16) * 32 + q * 8;
            aH[mt] = *(const bf16x8*)&AsH[rbase];
            if constexpr (!ABF16) aL[mt] = *(const bf16x8*)&AsL[rbase];
        }
        #pragma unroll
        for (int nt = 0; nt < 3; nt++) {
            int cbase = (wn * 48 + nt * 16 + r16) * 32 + q * 8;
            bH[nt] = *(const bf16x8*)&BsH[cbase];
            bL[nt] = *(const bf16x8*)&BsL[cbase];
        }
        // ---- MFMAs ----
        #pragma unroll
        for (int mt = 0; mt < 2; mt++)
            #pragma unroll
            for (int nt = 0; nt < 3; nt++) {
                acc[mt][nt] = __builtin_amdgcn_mfma_f32_16x16x32_bf16(aH[mt], bH[nt], acc[mt][nt], 0, 0, 0);
                acc[mt][nt] = __builtin_amdgcn_mfma_f32_16x16x32_bf16(aH[mt], bL[nt], acc[mt][nt], 0, 0, 0);
                if constexpr (!ABF16)
                    acc[mt][nt] = __builtin_amdgcn_mfma_f32_16x16x32_bf16(aL[mt], bH[nt], acc[mt][nt], 0, 0, 0);
            }
    }

    // ---- epilogue: D[row=(q*4+r)][col=r16] per 16x16 tile ----
    #pragma unroll
    for (int mt = 0; mt < 2; mt++) {
        #pragma unroll
        for (int nt = 0; nt < 3; nt++) {
            int col = bn + wn * 48 + nt * 16 + r16;
            float bv = bias[col];
            #pragma unroll
            for (int r = 0; r < 4; r++) {
                int row = bm + wm * 32 + mt * 16 + q * 4 + r;
                float val = acc[mt][nt][r] + bv;
                if (ACT == 1) val = gelu_exact(val);
                if (RES) val += res[(size_t)row * N + col];
                size_t orow;
                if (PERM) {
                    int b = row / LL;
                    int l = row - b * LL;
                    orow = (size_t)l * BB + b;
                } else {
                    orow = (size_t)row;
                }
                if constexpr (OUTBF16)
                    ((unsigned short*)outv)[orow * N + col] = f2bf(val);
                else
                    ((float*)outv)[orow * N + col] = val;
            }
        }
    }
}

// ---------------- CSR build ----------------
__global__ void hist_kernel(const int* __restrict__ ei, const int* __restrict__ et,
                            int* __restrict__ cnt)
{
    int e = blockIdx.x * 256 + threadIdx.x;
    if (e >= EE) return;
    int dst = ei[EE + e];
    int r   = et[e];
    atomicAdd(&cnt[dst * RR + r], 1);
}

// 1024-thread hierarchical block scan over NSEG=9408
__global__ __launch_bounds__(1024) void scan_kernel(const int* __restrict__ cnt,
                                                    int* __restrict__ colptr,
                                                    float* __restrict__ invcnt)
{
    __shared__ int wsum[16];
    int tid = threadIdx.x, wid = tid >> 6, lane = tid & 63;
    int carry = 0;
    for (int base = 0; base < NSEG; base += 1024) {
        int idx = base + tid;
        int v = (idx < NSEG) ? cnt[idx] : 0;
        if (idx < NSEG) invcnt[idx] = 1.f / (float)max(v, 1);
        int sc = v;
        #pragma unroll
        for (int off = 1; off < 64; off <<= 1) {
            int o = __shfl_up(sc, off);
            if (lane >= off) sc += o;
        }
        if (lane == 63) wsum[wid] = sc;
        __syncthreads();
        if (wid == 0) {
            int w = (lane < 16) ? wsum[lane] : 0;
            #pragma unroll
            for (int off = 1; off < 16; off <<= 1) {
                int o = __shfl_up(w, off);
                if (lane >= off) w += o;
            }
            if (lane < 16) wsum[lane] = w;
        }
        __syncthreads();
        int woff = (wid > 0) ? wsum[wid - 1] : 0;
        if (idx < NSEG) colptr[idx] = carry + woff + sc - v;   // exclusive
        carry += wsum[15];
        __syncthreads();
    }
    if (tid == 0) colptr[NSEG] = carry;
}

__global__ void scatter_kernel(const int* __restrict__ ei, const int* __restrict__ et,
                               const int* __restrict__ colptr, int* __restrict__ fill,
                               int* __restrict__ esorted)
{
    int e = blockIdx.x * 256 + threadIdx.x;
    if (e >= EE) return;
    int src = ei[e];
    int dst = ei[EE + e];
    int seg = dst * RR + et[e];
    int pos = colptr[seg] + atomicAdd(&fill[seg], 1);
    esorted[pos] = src;
}

// ---------------- Aggregation + depthwise convs + gating → updg bf16 [B,L,480] ----
// vp: bf16 [L][B][C]. 192 threads: thread = (b = t/12, group g = t%12, channels
// g*8..g*8+7). ONE dwordx4 (16B) load per edge per thread (vs 3 dwords before)
// -> 4x fewer memory instructions, better MLP. XCD-chunked block swizzle:
// consecutive l share an XCD's L2 (conv windows + distance-local graph edges).
__device__ __forceinline__ void unp8(const unsigned short* p, float* f) {
    u16x8 v = *(const u16x8*)p;
    #pragma unroll
    for (int j = 0; j < 8; j++) f[j] = bf2f(v[j]);
}
__device__ __forceinline__ void pack8(unsigned short* p, const float* f) {
    u16x8 v;
    #pragma unroll
    for (int j = 0; j < 8; j++) v[j] = f2bf(f[j]);
    *(u16x8*)p = v;
}

__global__ __launch_bounds__(192) void aggconv_kernel(
        const unsigned short* __restrict__ vp,
        const float* __restrict__ gate,
        const int* __restrict__ colptr, const int* __restrict__ esorted,
        const float* __restrict__ invcnt,
        const float* __restrict__ k3t, const float* __restrict__ b3,
        const float* __restrict__ k5t, const float* __restrict__ b5,
        unsigned short* __restrict__ updg)
{
    int bid = blockIdx.x;
    int l = (bid & 7) * (LL / 8) + (bid >> 3);   // XCD-chunked swizzle (3136 = 8*392)
    int t = threadIdx.x;
    int b = t / 12;          // 0..15
    int g = t - b * 12;      // 0..11
    int ch = g * 8;

    float gs[RTOT];
    #pragma unroll
    for (int r = 0; r < RTOT; r++) gs[r] = gate[((size_t)b * LL + l) * RTOT + r];
    size_t ob = ((size_t)b * LL + l) * (RTOT * CC);

    // graph relations: mean-aggregate
    #pragma unroll
    for (int r = 0; r < RR; r++) {
        int s0 = colptr[l * RR + r], s1 = colptr[l * RR + r + 1];
        float acc[8] = {0.f, 0.f, 0.f, 0.f, 0.f, 0.f, 0.f, 0.f};
        int src = (s0 < s1) ? esorted[s0] : 0;
        for (int e = s0; e < s1; e++) {
            int nsrc = (e + 1 < s1) ? esorted[e + 1] : 0;
            float f[8];
            unp8(vp + ((size_t)src * BB + b) * CC + ch, f);
            #pragma unroll
            for (int j = 0; j < 8; j++) acc[j] += f[j];
            src = nsrc;
        }
        float sc = invcnt[l * RR + r] * gs[r];
        float o[8];
        #pragma unroll
        for (int j = 0; j < 8; j++) o[j] = acc[j] * sc;
        pack8(updg + ob + r * CC + ch, o);
    }

    // context: 5x5 depthwise with fused 3x3 (3x3 taps subset of 5x5 window)
    int h0 = l / WW, w0 = l - (l / WW) * WW;
    float a3[8], a5[8];
    #pragma unroll
    for (int j = 0; j < 8; j++) { a3[j] = b3[ch + j]; a5[j] = b5[ch + j]; }
    #pragma unroll
    for (int kh = -2; kh <= 2; kh++) {
        int hh = h0 + kh; if (hh < 0 || hh >= HH) continue;
        #pragma unroll
        for (int kw = -2; kw <= 2; kw++) {
            int ww = w0 + kw; if (ww < 0 || ww >= WW) continue;
            float f[8];
            unp8(vp + ((size_t)(hh * WW + ww) * BB + b) * CC + ch, f);
            int tap5 = (kh + 2) * 5 + (kw + 2);
            const float* w5p = &k5t[tap5 * CC + ch];
            #pragma unroll
            for (int j = 0; j < 8; j++) a5[j] += f[j] * w5p[j];
            if (kh >= -1 && kh <= 1 && kw >= -1 && kw <= 1) {
                int tap3 = (kh + 1) * 3 + (kw + 1);
                const float* w3p = &k3t[tap3 * CC + ch];
                #pragma unroll
                for (int j = 0; j < 8; j++) a3[j] += f[j] * w3p[j];
            }
        }
    }
    float o3[8], o5[8];
    #pragma unroll
    for (int j = 0; j < 8; j++) { o3[j] = a3[j] * gs[3]; o5[j] = a5[j] * gs[4]; }
    pack8(updg + ob + 3 * CC + ch, o3);
    pack8(updg + ob + 4 * CC + ch, o5);
}

// ---------------- launch ----------------
extern "C" void kernel_launch(void* const* d_in, const int* in_sizes, int n_in,
                              void* d_out, int out_size, void* d_ws, size_t ws_size,
                              hipStream_t stream)
{
    const float* x       = (const float*)d_in[0];
    const int*   ei      = (const int*)d_in[1];
    const int*   et      = (const int*)d_in[2];
    // d_in[3], d_in[4] = H, W (hardcoded 56)
    const float* n1g     = (const float*)d_in[5];
    const float* n1b     = (const float*)d_in[6];
    const float* value_w = (const float*)d_in[7];
    const float* value_b = (const float*)d_in[8];
    const float* gate_w  = (const float*)d_in[9];
    const float* gate_b  = (const float*)d_in[10];
    const float* k3      = (const float*)d_in[11];
    const float* b3      = (const float*)d_in[12];
    const float* k5      = (const float*)d_in[13];
    const float* b5      = (const float*)d_in[14];
    const float* rel_w   = (const float*)d_in[15];
    const float* rel_b   = (const float*)d_in[16];
    const float* proj_w  = (const float*)d_in[17];
    const float* proj_b  = (const float*)d_in[18];
    const float* n2g     = (const float*)d_in[19];
    const float* n2b     = (const float*)d_in[20];
    const float* fc1_w   = (const float*)d_in[21];
    const float* fc1_b   = (const float*)d_in[22];
    const float* fc2_w   = (const float*)d_in[23];
    const float* fc2_b   = (const float*)d_in[24];
    float* out = (float*)d_out;

    // workspace layout (float extents kept; bf16 views carved inside)
    float* w = (float*)d_ws;
    const size_t SZ_ROW = (size_t)NR * CC;            // 4,816,896
    float* hbuf   = w;                                 // h (fp32), later g1_bf (bf16), later h2 (fp32)
    float* vbuf   = hbuf + SZ_ROW;                     // vp_bf (bf16 [L][B][C]), later x1 (fp32)
    float* gateb  = vbuf + SZ_ROW;                     // [NR,5]
    float* updg   = gateb + (size_t)NR * RTOT;         // updg_bf [NR,480] bf16, later hid_bf [NR,384] bf16
    int*   ibase  = (int*)(updg + (size_t)NR * RTOT * CC);
    int*   cnt     = ibase;                            // [NSEG]
    int*   colptr  = cnt + NSEG;                       // [NSEG+1]
    int*   fill    = colptr + NSEG + 1;                // [NSEG]
    int*   esorted = fill + NSEG;                      // [E]
    float* invcnt  = (float*)(esorted + EE);           // [NSEG]
    unsigned short* bhi = (unsigned short*)(invcnt + NSEG);  // [138240]
    unsigned short* blo = bhi + SPL_TOT;                     // [138240]
    float* k3t = (float*)(blo + SPL_TOT);              // [9*96]
    float* k5t = k3t + 864;                            // [25*96]

    unsigned short* vp_bf   = (unsigned short*)vbuf;
    unsigned short* g1_bf   = (unsigned short*)hbuf;
    unsigned short* updg_bf = (unsigned short*)updg;
    unsigned short* hid_bf  = (unsigned short*)updg;
    float* x1 = vbuf;

    // zero the counters
    hipMemsetAsync(cnt, 0, NSEG * sizeof(int), stream);
    hipMemsetAsync(fill, 0, NSEG * sizeof(int), stream);

    // 0. weight prep
    prep_split<<<(SPL_TOT + 255) / 256, 256, 0, stream>>>(value_w, rel_w, proj_w, fc1_w, fc2_w, bhi, blo);
    prep_convw<<<(864 + 2400 + 255) / 256, 256, 0, stream>>>(k3, k5, k3t, k5t);
    // 1. LN1 + fused gate: x -> h (fp32), gateb
    ln_kernel<true><<<NR / 4, 256, 0, stream>>>(x, n1g, n1b, hbuf, gate_w, gate_b, gateb, NR);
    // 2. vp_bf[l,b,:] = bf16(h @ value_w + value_b)  (PERM + OUTBF16)
    gemm_mfma<0, false, true, false, true><<<dim3(NR / 64, 1), 256, 0, stream>>>(hbuf, bhi + 0, blo + 0, value_b, nullptr, vp_bf, NR, 96, 96);
    // 3. CSR build
    hist_kernel<<<EE / 256, 256, 0, stream>>>(ei, et, cnt);
    scan_kernel<<<1, 1024, 0, stream>>>(cnt, colptr, invcnt);
    scatter_kernel<<<EE / 256, 256, 0, stream>>>(ei, et, colptr, fill, esorted);
    // 4. aggregation + convs + gating -> updg_bf  (dwordx4 gathers, XCD swizzle)
    aggconv_kernel<<<dim3(LL), 192, 0, stream>>>(vp_bf, gateb, colptr, esorted, invcnt,
                                                 k3t, b3, k5t, b5, updg_bf);
    // 5. g1_bf = bf16(gelu(updg @ rel_w + rel_b))  (ABF16 + OUTBF16, into hbuf region)
    gemm_mfma<1, false, false, true, true><<<dim3(NR / 64, 1), 256, 0, stream>>>(updg_bf, bhi + 9216, blo + 9216, rel_b, nullptr, g1_bf, NR, 96, 480);
    // 6. x1 = x + g1 @ proj_w + proj_b  (ABF16, fp32 out into vbuf)
    gemm_mfma<0, true, false, true, false><<<dim3(NR / 64, 1), 256, 0, stream>>>(g1_bf, bhi + 55296, blo + 55296, proj_b, x, x1, NR, 96, 96);
    // 7. h2 = LN2(x1)  (fp32, into hbuf)
    ln_kernel<false><<<NR / 4, 256, 0, stream>>>(x1, n2g, n2b, hbuf, nullptr, nullptr, nullptr, NR);
    // 8. hid_bf = bf16(gelu(h2 @ fc1_w + fc1_b))  (OUTBF16, into updg region)
    gemm_mfma<1, false, false, false, true><<<dim3(NR / 64, 4), 256, 0, stream>>>(hbuf, bhi + 64512, blo + 64512, fc1_b, nullptr, hid_bf, NR, 384, 96);
    // 9. out = x1 + hid @ fc2_w + fc2_b  (ABF16, fp32 out)
    gemm_mfma<0, true, false, true, false><<<dim3(NR / 64, 1), 256, 0, stream>>>(hid_bf, bhi + 101376, blo + 101376, fc2_b, x1, out, NR, 96, 384);
}